// Round 3
// baseline (355.036 us; speedup 1.0000x reference)
//
#include <hip/hip_runtime.h>
#include <stdint.h>

typedef unsigned short u16;
typedef __bf16 bf16x8 __attribute__((ext_vector_type(8)));
typedef float f32x4 __attribute__((ext_vector_type(4)));

#define NB    64
#define CIN   128
#define COUT  256
// position grid: 32 cols x 28 rows (+2 halo rows) per image; p = y*32 + x.
// cols 28..31 are garbage lanes (outputs discarded); image stride 960.
// GLOBAL position axis: gp = n*960 + p, 0..61439 (layouts are contiguous in n,
// so M-tiles of 256 span image boundaries; epilogue decodes n = gp/960).
#define PIMG  960
#define PTOT  61440   // 64*960

// ---------------- workspace layout ----------------
// xt4: [sub4 = (py&1)*2+(px&1)][g16][gp 61440][8]  space-to-depth of padded x
// a1c: [g32][gp 61440][8]                           conv2 input, halo ring zero
// Bt1: [nt2][kc144][128][8]   kc = tap*16 + cin/8
// Bt2: [nt2][kc304][128][8]   kc = tap*32 + c/8 ; 288..303 = shortcut cin/8
static constexpr size_t XT4_BYTES = (size_t)64*PTOT*8*2;      // 62,914,560
static constexpr size_t A1C_BYTES = (size_t)32*PTOT*8*2;      // 31,457,280
static constexpr size_t BT1_BYTES = (size_t)2*144*128*8*2;    //    589,824
static constexpr size_t BT2_BYTES = (size_t)2*304*128*8*2;    //  1,245,184
static constexpr size_t OFF_XT4  = 0;
static constexpr size_t OFF_A1C  = OFF_XT4 + XT4_BYTES;
static constexpr size_t OFF_B1   = OFF_A1C + A1C_BYTES;
static constexpr size_t OFF_B2   = OFF_B1 + BT1_BYTES;
static constexpr size_t OFF_BETA = OFF_B2 + BT2_BYTES;        // 512 floats

// ---------------- helpers ----------------
static __device__ __forceinline__ u16 f2bf(float f) {        // RNE f32->bf16
  uint32_t u = __float_as_uint(f);
  u += 0x7fffu + ((u >> 16) & 1u);
  return (u16)(u >> 16);
}

typedef const __attribute__((address_space(1))) uint32_t* gas1;
typedef __attribute__((address_space(3))) uint32_t* las3;
// async global->LDS, 16B/lane; LDS dest = wave-uniform base + lane*16
static __device__ __forceinline__ void gl16(const void* g, void* l) {
  __builtin_amdgcn_global_load_lds((gas1)(uintptr_t)g,
                                   (las3)(uint32_t)(uintptr_t)l, 16, 0, 0);
}

// BFP-quant two values of the same 32-channel group (this lane holds channels
// g*32 + {l15, 16+l15}); group max via pairwise max + 4-step shfl_xor over the
// 16 lanes of the quad (all share one output row -> predicate is uniform).
static __device__ __forceinline__ void quant2(float v0, float v1, float& o0, float& o1) {
  float mx = fmaxf(v0, v1);
  mx = fmaxf(mx, __shfl_xor(mx, 1));
  mx = fmaxf(mx, __shfl_xor(mx, 2));
  mx = fmaxf(mx, __shfl_xor(mx, 4));
  mx = fmaxf(mx, __shfl_xor(mx, 8));
  mx = fmaxf(mx, 1e-12f);
  const int e = (int)(__float_as_uint(mx) >> 23) - 127;            // floor(log2)
  const float scale = __uint_as_float((uint32_t)(e + 121) << 23);  // 2^(e-6)
  const float invs  = __uint_as_float((uint32_t)(133 - e) << 23);  // 2^(6-e)
  o0 = fminf(rintf(v0 * invs), 127.f) * scale;   // inputs post-ReLU (>=0)
  o1 = fminf(rintf(v1 * invs), 127.f) * scale;
}

// ---------------- x: fp32 NCHW -> xt4 space-to-depth bf16 ----------------
__global__ void k_transpose(const float* __restrict__ x, u16* __restrict__ xt4) {
  __shared__ float s[32][33];
  const int ht = blockIdx.x, ct = blockIdx.y, n = blockIdx.z;
  const int t = threadIdx.x, tc = t >> 5, tw = t & 31;
  const float* src = x + ((size_t)(n*CIN + ct*32))*3136 + ht*32;
#pragma unroll
  for (int i = 0; i < 4; ++i)
    s[tc + i*8][tw] = src[(size_t)(tc + i*8)*3136 + tw];
  __syncthreads();
  const int c = ct*32 + tw;
#pragma unroll
  for (int i = 0; i < 4; ++i) {
    const int hwl = tc + i*8;
    const int hw = ht*32 + hwl;
    const int h = hw / 56, w = hw % 56;
    const int py = h + 1, px = w + 1;                 // padded coords 1..56
    const int sub = (py & 1)*2 + (px & 1);
    const int p = (py >> 1)*32 + (px >> 1);
    xt4[(((size_t)(sub*16 + (c >> 3))*64 + n)*PIMG + p)*8 + (c & 7)]
        = f2bf(s[tw][hwl]);
  }
}

// ---------------- weight quant + BN fold + pre-tile to LDS order ----------
__global__ void k_prep(const float* __restrict__ w1, const float* __restrict__ w2,
                       const float* __restrict__ wsc,
                       const float* __restrict__ g1, const float* __restrict__ b1,
                       const float* __restrict__ m1, const float* __restrict__ v1,
                       const float* __restrict__ g2, const float* __restrict__ b2,
                       const float* __restrict__ m2, const float* __restrict__ v2,
                       const float* __restrict__ gs, const float* __restrict__ bs,
                       const float* __restrict__ ms, const float* __restrict__ vs,
                       u16* __restrict__ B1, u16* __restrict__ B2,
                       float* __restrict__ beta)
{
  const int id = blockIdx.x*256 + threadIdx.x;
  if (id < 9216) {                       // w1: (o, ib, tap) blocks of 32 in-ch
    const int o = id / 36, rem = id % 36, ib = rem / 9, t = rem % 9;
    const float inv = g1[o] / sqrtf(v1[o] + 1e-5f);
    const float* base = w1 + (size_t)(o*CIN + ib*32)*9 + t;
    float mx = 0.f;
#pragma unroll 8
    for (int jj = 0; jj < 32; ++jj) mx = fmaxf(mx, fabsf(base[jj*9]));
    const float scale = fmaxf(mx, 1e-12f) / 127.0f;
#pragma unroll 8
    for (int jj = 0; jj < 32; ++jj) {
      float q = rintf(base[jj*9] / scale);
      q = fminf(fmaxf(q, -128.f), 127.f);
      const int kc = t*16 + ib*4 + (jj >> 3);
      B1[(((size_t)(o >> 7)*144 + kc)*128 + (o & 127))*8 + (jj & 7)]
          = f2bf(q * scale * inv);
    }
  } else if (id < 27648) {               // w2 -> Bt2 kc = t*32 + c/8
    const int id2 = id - 9216;
    const int o = id2 / 72, rem = id2 % 72, ib = rem / 9, t = rem % 9;
    const float inv = g2[o] / sqrtf(v2[o] + 1e-5f);
    const float* base = w2 + (size_t)(o*COUT + ib*32)*9 + t;
    float mx = 0.f;
#pragma unroll 8
    for (int jj = 0; jj < 32; ++jj) mx = fmaxf(mx, fabsf(base[jj*9]));
    const float scale = fmaxf(mx, 1e-12f) / 127.0f;
#pragma unroll 8
    for (int jj = 0; jj < 32; ++jj) {
      float q = rintf(base[jj*9] / scale);
      q = fminf(fmaxf(q, -128.f), 127.f);
      const int kc = t*32 + ib*4 + (jj >> 3);
      B2[(((size_t)(o >> 7)*304 + kc)*128 + (o & 127))*8 + (jj & 7)]
          = f2bf(q * scale * inv);
    }
  } else if (id < 28672) {               // ws (1x1) -> Bt2 kc = 288 + cin/8
    const int id3 = id - 27648;
    const int o = id3 >> 2, ib = id3 & 3;
    const float inv = gs[o] / sqrtf(vs[o] + 1e-5f);
    const float* base = wsc + (size_t)o*CIN + ib*32;
    float mx = 0.f;
#pragma unroll 8
    for (int jj = 0; jj < 32; ++jj) mx = fmaxf(mx, fabsf(base[jj]));
    const float scale = fmaxf(mx, 1e-12f) / 127.0f;
#pragma unroll 8
    for (int jj = 0; jj < 32; ++jj) {
      float q = rintf(base[jj] / scale);
      q = fminf(fmaxf(q, -128.f), 127.f);
      const int kc = 288 + ib*4 + (jj >> 3);
      B2[(((size_t)(o >> 7)*304 + kc)*128 + (o & 127))*8 + (jj & 7)]
          = f2bf(q * scale * inv);
    }
  } else if (id < 29184) {               // betas: [0..255]=bn1, [256..511]=bn2+bns
    const int id4 = id - 28672;
    const int which = id4 >> 8, o = id4 & 255;
    if (which == 0) {
      beta[o] = b1[o] - m1[o] * (g1[o] / sqrtf(v1[o] + 1e-5f));
    } else {
      beta[256 + o] = (b2[o] - m2[o] * (g2[o] / sqrtf(v2[o] + 1e-5f)))
                    + (bs[o] - ms[o] * (gs[o] / sqrtf(vs[o] + 1e-5f)));
    }
  }
}

// ---------------- implicit-GEMM conv, 256x128 tile, 4 waves ----------------
// Per-wave tile fattened to 128x64 (was 64x64): FLOP per LDS-lane-byte
// 32 -> 42.7, cutting the LDS read traffic that capped the 128x128 version at
// MfmaUtil ~36%. Block tile BM=256 x BN=128, waves 2Mx2N. M-tiles use the
// GLOBAL position axis (gp = n*960 + p, contiguous across images); epilogue
// decodes n/p with one compare-subtract and skips halo-row positions
// (rem >= 896) that tiles now cover. Grid 480 = 240 mtiles x 2 ntiles;
// 2 blocks/CU (VGPR-limited) x 256 CU = 512 capacity -> fully resident.
// 2-stage LDS ring (48 KB), counted vmcnt(6), lgkmcnt(0)-before-barrier#2
// race discipline identical to the verified Round-2 kernel.
// MODE 0: conv1 3x3 s2 from xt4 (space-to-depth), 36 ksteps; epi -> a1c
// MODE 1: conv2 3x3 s1 from a1c (72) + shortcut 1x1 s2 from xt4 sub(1,1) (4);
//         epi: +beta,ReLU,BFP -> out fp32 NCHW
template<int MODE>
__global__ __launch_bounds__(256, 2)
void gemm_k(const u16* __restrict__ Ag, const u16* __restrict__ Ag2,
            const u16* __restrict__ Bg, const float* __restrict__ beta,
            u16* __restrict__ a1c, float* __restrict__ of32)
{
  __shared__ __align__(16) u16 As[2][4][256][8];   // 32 KB
  __shared__ __align__(16) u16 Bs[2][4][128][8];   // 16 KB

  const int tid = threadIdx.x;
  const int wv  = tid >> 6;
  const int ln  = tid & 63;
  // XCD-contiguous swizzle: 480 blocks = 8 xcd x 60; each XCD gets 30
  // contiguous mtiles, both ntiles sequentially -> L2 locality.
  const int b   = blockIdx.x;
  const int xcd = b & 7, j = b >> 3;
  const int mtile = xcd*30 + (j % 30);
  const int ntile = j / 30;

  constexpr int NKA = (MODE == 0) ? 36 : 72;     // main-conv ksteps
  constexpr int NK  = (MODE == 0) ? 36 : 76;     // + shortcut slab
  constexpr int NKC = (MODE == 0) ? 144 : 304;   // B kchunks per ntile
  constexpr int GSH = (MODE == 0) ? 4 : 5;       // log2(g's per tap)

  const int gp0 = mtile * 256;                   // global position base

  const char* const Bb = (const char*)Bg + (size_t)ntile*NKC*2048 + (size_t)ln*16;

  // issue stage nk's loads into ring slot `slot`:
  // per wave: its kchunk's A slab (4 KB = 4 x 1KB lane-contiguous) + B (2 KB)
  auto issue = [&](int nk, int slot) {
    const int kc = nk*4 + wv;
    const char* a;
    if (MODE == 1 && nk >= NKA) {                // shortcut: xt4 sub(1,1)
      const int g = kc - 288;
      a = (const char*)Ag2 + ((size_t)(48 + g)*PTOT + gp0)*16;
    } else if (MODE == 0) {
      const int t = kc >> GSH, g = kc & ((1 << GSH) - 1);
      const int dy = t / 3, dx = t - dy*3;
      const int sub = (dy & 1)*2 + (dx & 1);
      a = (const char*)Ag +
          ((size_t)(sub*16 + g)*PTOT + gp0 + (dy >> 1)*32 + (dx >> 1))*16;
    } else {
      const int t = kc >> GSH, g = kc & ((1 << GSH) - 1);
      const int dy = t / 3, dx = t - dy*3;
      a = (const char*)Ag + ((size_t)g*PTOT + gp0 + dy*32 + dx)*16;
    }
    a += (size_t)ln*16;
    const char* bb = Bb + (size_t)kc*2048;
    char* la = (char*)&As[slot][wv][0][0];
    char* lb = (char*)&Bs[slot][wv][0][0];
    gl16(a,        la);
    gl16(a + 1024, la + 1024);
    gl16(a + 2048, la + 2048);
    gl16(a + 3072, la + 3072);
    gl16(bb,        lb);
    gl16(bb + 1024, lb + 1024);
  };

  const int quad = ln >> 4, l15 = ln & 15;
  const int m_off = (wv & 1)*128, n_off = (wv >> 1)*64;
  const u16* ra[8];
  const u16* rb[4];
#pragma unroll
  for (int i = 0; i < 8; ++i)
    ra[i] = As[0][quad][m_off + i*16 + l15];   // quad selects kchunk (k=quad*8)
#pragma unroll
  for (int i = 0; i < 4; ++i)
    rb[i] = Bs[0][quad][n_off + i*16 + l15];

  f32x4 acc[8][4];
#pragma unroll
  for (int i = 0; i < 8; ++i)
#pragma unroll
    for (int j2 = 0; j2 < 4; ++j2)
      acc[i][j2] = (f32x4){0.f, 0.f, 0.f, 0.f};

  // ---- prologue: fill the ring ----
  issue(0, 0);
  issue(1, 1);

  int buf = 0;
  for (int i = 0; i < NK; ++i) {
    // wait only the OLDEST stage's 6 loads, then sync
    if (i + 1 < NK)      asm volatile("s_waitcnt vmcnt(6)" ::: "memory");
    else                 asm volatile("s_waitcnt vmcnt(0)" ::: "memory");
    asm volatile("s_barrier" ::: "memory");

    const int aoff = buf * 8192;          // u16 per A stage (4*256*8)
    const int boff = buf * 4096;          // u16 per B stage (4*128*8)
    bf16x8 av[8], bv[4];
#pragma unroll
    for (int k = 0; k < 8; ++k) av[k] = *(const bf16x8*)(ra[k] + aoff);
#pragma unroll
    for (int k = 0; k < 4; ++k) bv[k] = *(const bf16x8*)(rb[k] + boff);
#pragma unroll
    for (int mi = 0; mi < 8; ++mi)
#pragma unroll
      for (int ni = 0; ni < 4; ++ni)
        acc[mi][ni] = __builtin_amdgcn_mfma_f32_16x16x32_bf16(av[mi], bv[ni], acc[mi][ni], 0, 0, 0);

    if (i + 2 < NK) {
      // ds_reads of slot `buf` must be COMPLETE (not just issued) before any
      // wave passes this barrier and overwrites the slot.
      asm volatile("s_waitcnt lgkmcnt(0)" ::: "memory");
      asm volatile("s_barrier" ::: "memory");
      issue(i + 2, buf);
    }
    buf ^= 1;
  }

  // -------- epilogue --------
  const int cbase = ntile*128 + n_off;
  float bt[4];
#pragma unroll
  for (int ni = 0; ni < 4; ++ni) bt[ni] = beta[cbase + ni*16 + l15];

  const int gpw = gp0 + m_off;          // wave-uniform
  const int n0  = gpw / 960;
  const int r0  = gpw % 960;

  if constexpr (MODE == 0) {
#pragma unroll
    for (int mi = 0; mi < 8; ++mi)
#pragma unroll
      for (int r = 0; r < 4; ++r) {
        const int lo  = r0 + mi*16 + quad*4 + r;      // < 1920
        const int loc = (lo >= 960) ? lo - 960 : lo;  // p within image
        if (loc < 896 && (loc & 31) < 28) {            // skip halo rows + cols
          const int gp = gpw + mi*16 + quad*4 + r;     // global position
          float v[4];
#pragma unroll
          for (int ni = 0; ni < 4; ++ni) v[ni] = fmaxf(acc[mi][ni][r] + bt[ni], 0.f);
#pragma unroll
          for (int g = 0; g < 2; ++g) {
            float o0, o1;
            quant2(v[2*g], v[2*g+1], o0, o1);
            // a1 position = gp + 33 (shift into halo frame); q*2^(e-6) exact
            const int c0 = cbase + (2*g)*16 + l15;
            const int c1 = c0 + 16;
            a1c[((size_t)(c0 >> 3)*PTOT + gp + 33)*8 + (c0 & 7)]
                = (u16)(__float_as_uint(o0) >> 16);
            a1c[((size_t)(c1 >> 3)*PTOT + gp + 33)*8 + (c1 & 7)]
                = (u16)(__float_as_uint(o1) >> 16);
          }
        }
      }
  } else {
#pragma unroll
    for (int mi = 0; mi < 8; ++mi) {
      float ov[4][4];                       // [ni][r]
#pragma unroll
      for (int r = 0; r < 4; ++r) {
        float v[4];
#pragma unroll
        for (int ni = 0; ni < 4; ++ni)
          v[ni] = fmaxf(acc[mi][ni][r] + bt[ni], 0.f);
#pragma unroll
        for (int g = 0; g < 2; ++g)
          quant2(v[2*g], v[2*g+1], ov[2*g][r], ov[2*g+1][r]);
      }
      const int lo   = r0 + mi*16 + quad*4;  // 4 consecutive x, same row
      const int nimg = (lo >= 960) ? n0 + 1 : n0;
      const int loc  = (lo >= 960) ? lo - 960 : lo;
      const int x0 = loc & 31, y = loc >> 5;
      if (x0 < 28 && loc < 896) {
#pragma unroll
        for (int ni = 0; ni < 4; ++ni) {
          const int c = cbase + ni*16 + l15;
          f32x4 val = { ov[ni][0], ov[ni][1], ov[ni][2], ov[ni][3] };
          *(f32x4*)(of32 + ((size_t)(nimg*COUT + c)*28 + y)*28 + x0) = val;
        }
      }
    }
  }
}

// ---------------- launch ----------------
extern "C" void kernel_launch(void* const* d_in, const int* in_sizes, int n_in,
                              void* d_out, int out_size, void* d_ws, size_t ws_size,
                              hipStream_t stream)
{
  (void)in_sizes; (void)n_in; (void)out_size; (void)ws_size;
  const float* x   = (const float*)d_in[0];
  const float* w1  = (const float*)d_in[1];
  const float* w2  = (const float*)d_in[2];
  const float* wsc = (const float*)d_in[3];
  const float* g1 = (const float*)d_in[4];
  const float* b1 = (const float*)d_in[5];
  const float* m1 = (const float*)d_in[6];
  const float* v1 = (const float*)d_in[7];
  const float* g2 = (const float*)d_in[8];
  const float* b2 = (const float*)d_in[9];
  const float* m2 = (const float*)d_in[10];
  const float* v2 = (const float*)d_in[11];
  const float* gs = (const float*)d_in[12];
  const float* bs = (const float*)d_in[13];
  const float* ms = (const float*)d_in[14];
  const float* vs = (const float*)d_in[15];

  char* ws = (char*)d_ws;
  u16* xt4  = (u16*)(ws + OFF_XT4);
  u16* a1c  = (u16*)(ws + OFF_A1C);
  u16* B1   = (u16*)(ws + OFF_B1);
  u16* B2   = (u16*)(ws + OFF_B2);
  float* beta = (float*)(ws + OFF_BETA);

  // zero halos + garbage lanes in one shot (xt4 and a1c are contiguous)
  hipMemsetAsync(ws, 0, OFF_B1, stream);

  k_transpose<<<dim3(98, 4, 64), 256, 0, stream>>>(x, xt4);
  k_prep<<<114, 256, 0, stream>>>(w1, w2, wsc, g1, b1, m1, v1,
                                  g2, b2, m2, v2, gs, bs, ms, vs,
                                  B1, B2, beta);
  gemm_k<0><<<480, 256, 0, stream>>>(xt4, nullptr, B1, beta, a1c, nullptr);
  gemm_k<1><<<480, 256, 0, stream>>>(a1c, xt4, B2, beta + 256, nullptr, (float*)d_out);
}

// Round 4
// 346.011 us; speedup vs baseline: 1.0261x; 1.0261x over previous
//
#include <hip/hip_runtime.h>
#include <stdint.h>

typedef unsigned short u16;
typedef __bf16 bf16x8 __attribute__((ext_vector_type(8)));
typedef float f32x4 __attribute__((ext_vector_type(4)));

#define NB    64
#define CIN   128
#define COUT  256
// position grid: 32 cols x 28 rows (+2 halo rows) per image; p = y*32 + x.
// cols 28..31 are garbage lanes (outputs discarded); image stride 960.
// GLOBAL position axis: gp = n*960 + p, 0..61439 (layouts contiguous in n).
#define PIMG  960
#define PTOT  61440   // 64*960

// ---------------- workspace layout ----------------
// xt4: [sub4 = (py&1)*2+(px&1)][g16][gp 61440][8]  space-to-depth of padded x
// a1c: [g32][gp 61440][8]                           conv2 input, halo ring zero
// Bt1: [nt2][kc144][128][8]   kc = tap*16 + cin/8
// Bt2: [nt2][kc304][128][8]   kc = tap*32 + c/8 ; 288..303 = shortcut cin/8
static constexpr size_t XT4_BYTES = (size_t)64*PTOT*8*2;      // 62,914,560
static constexpr size_t A1C_BYTES = (size_t)32*PTOT*8*2;      // 31,457,280
static constexpr size_t BT1_BYTES = (size_t)2*144*128*8*2;    //    589,824
static constexpr size_t BT2_BYTES = (size_t)2*304*128*8*2;    //  1,245,184
static constexpr size_t OFF_XT4  = 0;
static constexpr size_t OFF_A1C  = OFF_XT4 + XT4_BYTES;
static constexpr size_t OFF_B1   = OFF_A1C + A1C_BYTES;
static constexpr size_t OFF_B2   = OFF_B1 + BT1_BYTES;
static constexpr size_t OFF_BETA = OFF_B2 + BT2_BYTES;        // 512 floats

// ---------------- helpers ----------------
static __device__ __forceinline__ u16 f2bf(float f) {        // RNE f32->bf16
  uint32_t u = __float_as_uint(f);
  u += 0x7fffu + ((u >> 16) & 1u);
  return (u16)(u >> 16);
}

typedef const __attribute__((address_space(1))) uint32_t* gas1;
typedef __attribute__((address_space(3))) uint32_t* las3;
// async global->LDS, 16B/lane; LDS dest = wave-uniform base + lane*16
static __device__ __forceinline__ void gl16(const void* g, void* l) {
  __builtin_amdgcn_global_load_lds((gas1)(uintptr_t)g,
                                   (las3)(uint32_t)(uintptr_t)l, 16, 0, 0);
}

// BFP-quant two values of the same 32-channel group (this lane holds channels
// g*32 + {l15, 16+l15}); group max via pairwise max + 4-step shfl_xor over the
// 16 lanes of the quad (all share one output row -> predicate is uniform).
static __device__ __forceinline__ void quant2(float v0, float v1, float& o0, float& o1) {
  float mx = fmaxf(v0, v1);
  mx = fmaxf(mx, __shfl_xor(mx, 1));
  mx = fmaxf(mx, __shfl_xor(mx, 2));
  mx = fmaxf(mx, __shfl_xor(mx, 4));
  mx = fmaxf(mx, __shfl_xor(mx, 8));
  mx = fmaxf(mx, 1e-12f);
  const int e = (int)(__float_as_uint(mx) >> 23) - 127;            // floor(log2)
  const float scale = __uint_as_float((uint32_t)(e + 121) << 23);  // 2^(e-6)
  const float invs  = __uint_as_float((uint32_t)(133 - e) << 23);  // 2^(6-e)
  o0 = fminf(rintf(v0 * invs), 127.f) * scale;   // inputs post-ReLU (>=0)
  o1 = fminf(rintf(v1 * invs), 127.f) * scale;
}

// ---------------- x: fp32 NCHW -> xt4 space-to-depth bf16 ----------------
__global__ void k_transpose(const float* __restrict__ x, u16* __restrict__ xt4) {
  __shared__ float s[32][33];
  const int ht = blockIdx.x, ct = blockIdx.y, n = blockIdx.z;
  const int t = threadIdx.x, tc = t >> 5, tw = t & 31;
  const float* src = x + ((size_t)(n*CIN + ct*32))*3136 + ht*32;
#pragma unroll
  for (int i = 0; i < 4; ++i)
    s[tc + i*8][tw] = src[(size_t)(tc + i*8)*3136 + tw];
  __syncthreads();
  const int c = ct*32 + tw;
#pragma unroll
  for (int i = 0; i < 4; ++i) {
    const int hwl = tc + i*8;
    const int hw = ht*32 + hwl;
    const int h = hw / 56, w = hw % 56;
    const int py = h + 1, px = w + 1;                 // padded coords 1..56
    const int sub = (py & 1)*2 + (px & 1);
    const int p = (py >> 1)*32 + (px >> 1);
    xt4[(((size_t)(sub*16 + (c >> 3))*64 + n)*PIMG + p)*8 + (c & 7)]
        = f2bf(s[tw][hwl]);
  }
}

// ---------------- weight quant + BN fold + pre-tile to LDS order ----------
__global__ void k_prep(const float* __restrict__ w1, const float* __restrict__ w2,
                       const float* __restrict__ wsc,
                       const float* __restrict__ g1, const float* __restrict__ b1,
                       const float* __restrict__ m1, const float* __restrict__ v1,
                       const float* __restrict__ g2, const float* __restrict__ b2,
                       const float* __restrict__ m2, const float* __restrict__ v2,
                       const float* __restrict__ gs, const float* __restrict__ bs,
                       const float* __restrict__ ms, const float* __restrict__ vs,
                       u16* __restrict__ B1, u16* __restrict__ B2,
                       float* __restrict__ beta)
{
  const int id = blockIdx.x*256 + threadIdx.x;
  if (id < 9216) {                       // w1: (o, ib, tap) blocks of 32 in-ch
    const int o = id / 36, rem = id % 36, ib = rem / 9, t = rem % 9;
    const float inv = g1[o] / sqrtf(v1[o] + 1e-5f);
    const float* base = w1 + (size_t)(o*CIN + ib*32)*9 + t;
    float mx = 0.f;
#pragma unroll 8
    for (int jj = 0; jj < 32; ++jj) mx = fmaxf(mx, fabsf(base[jj*9]));
    const float scale = fmaxf(mx, 1e-12f) / 127.0f;
#pragma unroll 8
    for (int jj = 0; jj < 32; ++jj) {
      float q = rintf(base[jj*9] / scale);
      q = fminf(fmaxf(q, -128.f), 127.f);
      const int kc = t*16 + ib*4 + (jj >> 3);
      B1[(((size_t)(o >> 7)*144 + kc)*128 + (o & 127))*8 + (jj & 7)]
          = f2bf(q * scale * inv);
    }
  } else if (id < 27648) {               // w2 -> Bt2 kc = t*32 + c/8
    const int id2 = id - 9216;
    const int o = id2 / 72, rem = id2 % 72, ib = rem / 9, t = rem % 9;
    const float inv = g2[o] / sqrtf(v2[o] + 1e-5f);
    const float* base = w2 + (size_t)(o*COUT + ib*32)*9 + t;
    float mx = 0.f;
#pragma unroll 8
    for (int jj = 0; jj < 32; ++jj) mx = fmaxf(mx, fabsf(base[jj*9]));
    const float scale = fmaxf(mx, 1e-12f) / 127.0f;
#pragma unroll 8
    for (int jj = 0; jj < 32; ++jj) {
      float q = rintf(base[jj*9] / scale);
      q = fminf(fmaxf(q, -128.f), 127.f);
      const int kc = t*32 + ib*4 + (jj >> 3);
      B2[(((size_t)(o >> 7)*304 + kc)*128 + (o & 127))*8 + (jj & 7)]
          = f2bf(q * scale * inv);
    }
  } else if (id < 28672) {               // ws (1x1) -> Bt2 kc = 288 + cin/8
    const int id3 = id - 27648;
    const int o = id3 >> 2, ib = id3 & 3;
    const float inv = gs[o] / sqrtf(vs[o] + 1e-5f);
    const float* base = wsc + (size_t)o*CIN + ib*32;
    float mx = 0.f;
#pragma unroll 8
    for (int jj = 0; jj < 32; ++jj) mx = fmaxf(mx, fabsf(base[jj]));
    const float scale = fmaxf(mx, 1e-12f) / 127.0f;
#pragma unroll 8
    for (int jj = 0; jj < 32; ++jj) {
      float q = rintf(base[jj] / scale);
      q = fminf(fmaxf(q, -128.f), 127.f);
      const int kc = 288 + ib*4 + (jj >> 3);
      B2[(((size_t)(o >> 7)*304 + kc)*128 + (o & 127))*8 + (jj & 7)]
          = f2bf(q * scale * inv);
    }
  } else if (id < 29184) {               // betas: [0..255]=bn1, [256..511]=bn2+bns
    const int id4 = id - 28672;
    const int which = id4 >> 8, o = id4 & 255;
    if (which == 0) {
      beta[o] = b1[o] - m1[o] * (g1[o] / sqrtf(v1[o] + 1e-5f));
    } else {
      beta[256 + o] = (b2[o] - m2[o] * (g2[o] / sqrtf(v2[o] + 1e-5f)))
                    + (bs[o] - ms[o] * (gs[o] / sqrtf(vs[o] + 1e-5f)));
    }
  }
}

// ------------- implicit-GEMM conv, 256x256 tile, 8 waves, K64 phases -------
// 8-wave (2M x 4N) block, per-wave output 128x64, BN=256 = full COUT so the
// ntile axis disappears: grid 240 = one block per CU, fully resident.
// LDS 160 KB: A ring 3 x 32KB (K64 slab), B ring 2 x 32KB. The 3rd A slot
// lets A-staging for tile kt+2 issue INSIDE the compute phases (its slot was
// freed by iteration kt-1's tail barrier) -> fine ds_read||G-load||MFMA
// interleave. B(kt+2) bursts after the tail barrier (its slot is freed only
// then), overlapped with the last MFMA cluster.
// Counted vmcnt: 8 loads/wave/tile (4A+4B); vmcnt(8) at iteration top drains
// exactly tile kt while kt+1's 8 stay in flight (2-iteration latency cover).
// WAR discipline (verified): every ds_read is a C-level memory op pinned by
// the asm "memory" clobbers; each wave executes lgkmcnt(0) before the tail
// barrier, so all reads of a slot COMPLETE before any wave refills it.
// MODE 0: conv1 3x3 s2 from xt4, 18 K64-tiles; epi -> a1c (BFP quant)
// MODE 1: conv2 3x3 s1 from a1c (36) + shortcut 1x1 s2 from xt4 sub(1,1) (2);
//         epi: +beta,ReLU,BFP -> out fp32 NCHW
template<int MODE>
__global__ __launch_bounds__(512, 2)
void gemm_k(const u16* __restrict__ Ag, const u16* __restrict__ Ag2,
            const u16* __restrict__ Bg, const float* __restrict__ beta,
            u16* __restrict__ a1c, float* __restrict__ of32)
{
  __shared__ __align__(16) u16 As3[3][8][256][8];      // 96 KB
  __shared__ __align__(16) u16 Bs2[2][8][2][128][8];   // 64 KB

  const int tid = threadIdx.x;
  const int wv  = tid >> 6;          // 0..7
  const int ln  = tid & 63;
  const int wr  = wv >> 2;           // 0..1  M-half
  const int wc  = wv & 3;            // 0..3  N-quarter

  // XCD-contiguous swizzle: 240 = 8 xcd x 30 contiguous mtiles
  const int b = blockIdx.x;
  const int mtile = (b & 7)*30 + (b >> 3);
  const int gp0 = mtile * 256;

  constexpr int NT  = (MODE == 0) ? 18 : 38;   // K64 tiles
  constexpr int NKC = (MODE == 0) ? 144 : 304; // B kchunks per ntile

  // A staging source (wave-uniform base) for kchunk kc
  auto a_src = [&](int kc) -> const char* {
    if (MODE == 1 && kc >= 288) {              // shortcut: xt4 sub(1,1)
      const int g = kc - 288;
      return (const char*)Ag2 + ((size_t)(48 + g)*PTOT + gp0)*16;
    } else if (MODE == 0) {
      const int t = kc >> 4, g = kc & 15;
      const int dy = t/3, dx = t - dy*3;
      const int sub = (dy & 1)*2 + (dx & 1);
      return (const char*)Ag +
             ((size_t)(sub*16 + g)*PTOT + gp0 + (dy >> 1)*32 + (dx >> 1))*16;
    } else {
      const int t = kc >> 5, g = kc & 31;
      const int dy = t/3, dx = t - dy*3;
      return (const char*)Ag + ((size_t)g*PTOT + gp0 + dy*32 + dx)*16;
    }
  };

  // stage tile kt2's A slab for this wave's kchunk (4 KB = 4 x 1KB)
  auto issueA4 = [&](int kt2, int slot) {
    const char* s = a_src(kt2*8 + wv) + (size_t)ln*16;
    char* d = (char*)&As3[slot][wv][0][0];
#pragma unroll
    for (int q = 0; q < 4; ++q) gl16(s + q*1024, d + q*1024);
  };
  // stage tile kt2's B slabs (both ntile halves, 2 x 2KB)
  auto issueB4 = [&](int kt2, int slot) {
    const int kc = kt2*8 + wv;
    const char* s0 = (const char*)Bg + (size_t)kc*2048 + (size_t)ln*16;
    const char* s1 = s0 + (size_t)NKC*2048;
    char* d = (char*)&Bs2[slot][wv][0][0][0];
    gl16(s0,        d);
    gl16(s0 + 1024, d + 1024);
    gl16(s1,        d + 2048);
    gl16(s1 + 1024, d + 3072);
  };

  const int quad = ln >> 4, l15 = ln & 15;
  // LDS read bases: strides (u16): kchunk 2048, ks(4 kchunks) 8192, slot 16384
  const u16* aP = &As3[0][quad][wr*128 + l15][0];
  const u16* bP[4];
#pragma unroll
  for (int ni = 0; ni < 4; ++ni) {
    const int n_ = wc*64 + ni*16 + l15;
    bP[ni] = &Bs2[0][quad][n_ >> 7][n_ & 127][0];
  }

  f32x4 acc[8][4];
#pragma unroll
  for (int i = 0; i < 8; ++i)
#pragma unroll
    for (int j2 = 0; j2 < 4; ++j2)
      acc[i][j2] = (f32x4){0.f, 0.f, 0.f, 0.f};

  // ---- prologue: stage tiles 0 and 1 ----
  issueA4(0, 0); issueB4(0, 0);
  issueA4(1, 1); issueB4(1, 1);

  int sl = 0;                                  // kt % 3 (A slot)
  for (int kt = 0; kt < NT; ++kt) {
    const int bsl = kt & 1;                    // B slot
    if (kt + 1 < NT) asm volatile("s_waitcnt vmcnt(8)" ::: "memory");
    else             asm volatile("s_waitcnt vmcnt(0)" ::: "memory");
    asm volatile("s_barrier" ::: "memory");    // tile kt fully in LDS

    // B fragments for the whole K64 tile (held in regs across phases)
    bf16x8 bv[4][2];
#pragma unroll
    for (int ni = 0; ni < 4; ++ni)
#pragma unroll
      for (int ks = 0; ks < 2; ++ks)
        bv[ni][ks] = *(const bf16x8*)(bP[ni] + bsl*16384 + ks*8192);

    const u16* aB = aP + sl*16384;
    const bool pre = (kt + 2 < NT);
    int s2 = sl + 2; if (s2 >= 3) s2 -= 3;     // (kt+2) % 3
    const char* asrc = nullptr; char* adst = nullptr;
    if (pre) {
      asrc = a_src((kt + 2)*8 + wv) + (size_t)ln*16;
      adst = (char*)&As3[s2][wv][0][0];
    }

#pragma unroll
    for (int ph = 0; ph < 4; ++ph) {
      bf16x8 av[2][2];
#pragma unroll
      for (int q = 0; q < 2; ++q)
#pragma unroll
        for (int ks = 0; ks < 2; ++ks)
          av[q][ks] = *(const bf16x8*)(aB + ks*8192 + (ph*2 + q)*128);
      if (pre) gl16(asrc + ph*1024, adst + ph*1024);   // A(kt+2) part ph
      asm volatile("s_waitcnt lgkmcnt(0)" ::: "memory");
      __builtin_amdgcn_sched_barrier(0);
      if (ph == 3) {
        // every wave has lgkmcnt(0)'d all its reads of tile kt before this
        // barrier -> safe to overwrite B slot bsl ( == (kt+2)&1 )
        asm volatile("s_barrier" ::: "memory");
        if (pre) issueB4(kt + 2, bsl);
      }
      __builtin_amdgcn_s_setprio(1);
#pragma unroll
      for (int q = 0; q < 2; ++q) {
        const int mi = ph*2 + q;
#pragma unroll
        for (int ni = 0; ni < 4; ++ni) {
          acc[mi][ni] = __builtin_amdgcn_mfma_f32_16x16x32_bf16(av[q][0], bv[ni][0], acc[mi][ni], 0, 0, 0);
          acc[mi][ni] = __builtin_amdgcn_mfma_f32_16x16x32_bf16(av[q][1], bv[ni][1], acc[mi][ni], 0, 0, 0);
        }
      }
      __builtin_amdgcn_s_setprio(0);
    }
    sl = (sl == 2) ? 0 : sl + 1;
  }

  // -------- epilogue --------
  const int cbase = wc*64;
  float bt[4];
#pragma unroll
  for (int ni = 0; ni < 4; ++ni) bt[ni] = beta[cbase + ni*16 + l15];

  const int gpw = gp0 + wr*128;         // wave-uniform
  const int n0  = gpw / 960;
  const int r0  = gpw % 960;

  if constexpr (MODE == 0) {
#pragma unroll
    for (int mi = 0; mi < 8; ++mi)
#pragma unroll
      for (int r = 0; r < 4; ++r) {
        const int lo  = r0 + mi*16 + quad*4 + r;      // < 1920
        const int loc = (lo >= 960) ? lo - 960 : lo;  // p within image
        if (loc < 896 && (loc & 31) < 28) {            // skip halo rows + cols
          const int gp = gpw + mi*16 + quad*4 + r;     // global position
          float v[4];
#pragma unroll
          for (int ni = 0; ni < 4; ++ni) v[ni] = fmaxf(acc[mi][ni][r] + bt[ni], 0.f);
#pragma unroll
          for (int g = 0; g < 2; ++g) {
            float o0, o1;
            quant2(v[2*g], v[2*g+1], o0, o1);
            // a1 position = gp + 33 (shift into halo frame); q*2^(e-6) exact
            const int c0 = cbase + (2*g)*16 + l15;
            const int c1 = c0 + 16;
            a1c[((size_t)(c0 >> 3)*PTOT + gp + 33)*8 + (c0 & 7)]
                = (u16)(__float_as_uint(o0) >> 16);
            a1c[((size_t)(c1 >> 3)*PTOT + gp + 33)*8 + (c1 & 7)]
                = (u16)(__float_as_uint(o1) >> 16);
          }
        }
      }
  } else {
#pragma unroll
    for (int mi = 0; mi < 8; ++mi) {
      float ov[4][4];                       // [ni][r]
#pragma unroll
      for (int r = 0; r < 4; ++r) {
        float v[4];
#pragma unroll
        for (int ni = 0; ni < 4; ++ni)
          v[ni] = fmaxf(acc[mi][ni][r] + bt[ni], 0.f);
#pragma unroll
        for (int g = 0; g < 2; ++g)
          quant2(v[2*g], v[2*g+1], ov[2*g][r], ov[2*g+1][r]);
      }
      const int lo   = r0 + mi*16 + quad*4;  // 4 consecutive x, same row
      const int nimg = (lo >= 960) ? n0 + 1 : n0;
      const int loc  = (lo >= 960) ? lo - 960 : lo;
      const int x0 = loc & 31, y = loc >> 5;
      if (x0 < 28 && loc < 896) {
#pragma unroll
        for (int ni = 0; ni < 4; ++ni) {
          const int c = cbase + ni*16 + l15;
          f32x4 val = { ov[ni][0], ov[ni][1], ov[ni][2], ov[ni][3] };
          *(f32x4*)(of32 + ((size_t)(nimg*COUT + c)*28 + y)*28 + x0) = val;
        }
      }
    }
  }
}

// ---------------- launch ----------------
extern "C" void kernel_launch(void* const* d_in, const int* in_sizes, int n_in,
                              void* d_out, int out_size, void* d_ws, size_t ws_size,
                              hipStream_t stream)
{
  (void)in_sizes; (void)n_in; (void)out_size; (void)ws_size;
  const float* x   = (const float*)d_in[0];
  const float* w1  = (const float*)d_in[1];
  const float* w2  = (const float*)d_in[2];
  const float* wsc = (const float*)d_in[3];
  const float* g1 = (const float*)d_in[4];
  const float* b1 = (const float*)d_in[5];
  const float* m1 = (const float*)d_in[6];
  const float* v1 = (const float*)d_in[7];
  const float* g2 = (const float*)d_in[8];
  const float* b2 = (const float*)d_in[9];
  const float* m2 = (const float*)d_in[10];
  const float* v2 = (const float*)d_in[11];
  const float* gs = (const float*)d_in[12];
  const float* bs = (const float*)d_in[13];
  const float* ms = (const float*)d_in[14];
  const float* vs = (const float*)d_in[15];

  char* ws = (char*)d_ws;
  u16* xt4  = (u16*)(ws + OFF_XT4);
  u16* a1c  = (u16*)(ws + OFF_A1C);
  u16* B1   = (u16*)(ws + OFF_B1);
  u16* B2   = (u16*)(ws + OFF_B2);
  float* beta = (float*)(ws + OFF_BETA);

  // zero halos + garbage lanes in one shot (xt4 and a1c are contiguous)
  hipMemsetAsync(ws, 0, OFF_B1, stream);

  k_transpose<<<dim3(98, 4, 64), 256, 0, stream>>>(x, xt4);
  k_prep<<<114, 256, 0, stream>>>(w1, w2, wsc, g1, b1, m1, v1,
                                  g2, b2, m2, v2, gs, bs, ms, vs,
                                  B1, B2, beta);
  gemm_k<0><<<240, 512, 0, stream>>>(xt4, nullptr, B1, beta, a1c, nullptr);
  gemm_k<1><<<240, 512, 0, stream>>>(a1c, xt4, B2, beta + 256, nullptr, (float*)d_out);
}